// Round 3
// baseline (272.697 us; speedup 1.0000x reference)
//
#include <hip/hip_runtime.h>

#define B_ROWS 4096
#define N_COLS 8192
#define BLOCK  256
#define VPT    (N_COLS / 4 / BLOCK)   // float4 loads per thread per input = 8

// One block per row: 5 fused reductions + per-row loss.
//
// R1/R2 lesson: with default __launch_bounds__(256) the machine scheduler
// targets max occupancy, sinks loads next to their uses (VGPR_Count=32,
// ~2 float4 in flight), and the kernel is MLP-starved at 2.7 TB/s effective.
// __launch_bounds__(256, 2) relaxes the VGPR budget to 256 so the scheduler
// can keep all 16 global_load_dwordx4 in flight before the first waitcnt.
__global__ __launch_bounds__(BLOCK, 2) void row_pearson_kernel(
    const float* __restrict__ preds,
    const float* __restrict__ labels,
    float* __restrict__ row_loss)
{
    const int row = blockIdx.x;
    const int tid = threadIdx.x;

    const float4* p4 = reinterpret_cast<const float4*>(preds  + (size_t)row * N_COLS);
    const float4* l4 = reinterpret_cast<const float4*>(labels + (size_t)row * N_COLS);

    // Batch ALL 16 loads (256 B/thread, 16 KB/wave in flight).
    float4 x[VPT], y[VPT];
    #pragma unroll
    for (int i = 0; i < VPT; ++i) {
        x[i] = p4[tid + i * BLOCK];
        y[i] = l4[tid + i * BLOCK];
    }

    // Two independent accumulator sets to shorten the FMA dep chain.
    float sx0 = 0.f, sy0 = 0.f, sxy0 = 0.f, sxx0 = 0.f, syy0 = 0.f;
    float sx1 = 0.f, sy1 = 0.f, sxy1 = 0.f, sxx1 = 0.f, syy1 = 0.f;
    #pragma unroll
    for (int i = 0; i < VPT; i += 2) {
        {
            const float4 a = x[i], b = y[i];
            sx0  += a.x + a.y + a.z + a.w;
            sy0  += b.x + b.y + b.z + b.w;
            sxy0 += a.x * b.x + a.y * b.y + a.z * b.z + a.w * b.w;
            sxx0 += a.x * a.x + a.y * a.y + a.z * a.z + a.w * a.w;
            syy0 += b.x * b.x + b.y * b.y + b.z * b.z + b.w * b.w;
        }
        {
            const float4 a = x[i + 1], b = y[i + 1];
            sx1  += a.x + a.y + a.z + a.w;
            sy1  += b.x + b.y + b.z + b.w;
            sxy1 += a.x * b.x + a.y * b.y + a.z * b.z + a.w * b.w;
            sxx1 += a.x * a.x + a.y * a.y + a.z * a.z + a.w * a.w;
            syy1 += b.x * b.x + b.y * b.y + b.z * b.z + b.w * b.w;
        }
    }
    float sx = sx0 + sx1, sy = sy0 + sy1, sxy = sxy0 + sxy1;
    float sxx = sxx0 + sxx1, syy = syy0 + syy1;

    // 64-lane wave reduction (wave = 64 on gfx950).
    #pragma unroll
    for (int off = 32; off > 0; off >>= 1) {
        sx  += __shfl_down(sx,  off);
        sy  += __shfl_down(sy,  off);
        sxy += __shfl_down(sxy, off);
        sxx += __shfl_down(sxx, off);
        syy += __shfl_down(syy, off);
    }

    __shared__ float smem[4][5];   // 4 waves per block
    const int wave = tid >> 6;
    const int lane = tid & 63;
    if (lane == 0) {
        smem[wave][0] = sx;  smem[wave][1] = sy;  smem[wave][2] = sxy;
        smem[wave][3] = sxx; smem[wave][4] = syy;
    }
    __syncthreads();

    if (tid == 0) {
        float tx = 0.f, ty = 0.f, txy = 0.f, txx = 0.f, tyy = 0.f;
        #pragma unroll
        for (int w = 0; w < BLOCK / 64; ++w) {
            tx  += smem[w][0]; ty  += smem[w][1]; txy += smem[w][2];
            txx += smem[w][3]; tyy += smem[w][4];
        }
        const float Nf  = (float)N_COLS;
        const float num = Nf * txy - tx * ty;
        const float den = sqrtf((Nf * txx - tx * tx) * (Nf * tyy - ty * ty));
        row_loss[row] = 1.0f - num / den;
    }
}

// Reduce 4096 per-row losses to the mean. Single block.
__global__ __launch_bounds__(BLOCK) void mean_kernel(
    const float* __restrict__ row_loss,
    float* __restrict__ out)
{
    const int tid = threadIdx.x;

    float v[B_ROWS / BLOCK];
    #pragma unroll
    for (int i = 0; i < B_ROWS / BLOCK; ++i)
        v[i] = row_loss[tid + i * BLOCK];

    float s = 0.f;
    #pragma unroll
    for (int i = 0; i < B_ROWS / BLOCK; ++i)
        s += v[i];

    #pragma unroll
    for (int off = 32; off > 0; off >>= 1)
        s += __shfl_down(s, off);

    __shared__ float smem[4];
    const int wave = tid >> 6;
    const int lane = tid & 63;
    if (lane == 0) smem[wave] = s;
    __syncthreads();

    if (tid == 0) {
        float t = smem[0] + smem[1] + smem[2] + smem[3];
        out[0] = t / (float)B_ROWS;
    }
}

extern "C" void kernel_launch(void* const* d_in, const int* in_sizes, int n_in,
                              void* d_out, int out_size, void* d_ws, size_t ws_size,
                              hipStream_t stream) {
    const float* preds  = (const float*)d_in[0];
    const float* labels = (const float*)d_in[1];
    float* row_loss = (float*)d_ws;      // 4096 floats of scratch
    float* out      = (float*)d_out;

    row_pearson_kernel<<<B_ROWS, BLOCK, 0, stream>>>(preds, labels, row_loss);
    mean_kernel<<<1, BLOCK, 0, stream>>>(row_loss, out);
}